// Round 8
// baseline (179.477 us; speedup 1.0000x reference)
//
#include <hip/hip_runtime.h>

#define M_NODES 16384
#define NNBR 32
#define RREL 237
#define ATTN_SCALE 0.25f   // (128/8)^-0.5
#define LN_EPS 1e-5f

typedef float float4v __attribute__((ext_vector_type(4)));
typedef float float2v __attribute__((ext_vector_type(2)));
typedef unsigned int uint4v __attribute__((ext_vector_type(4)));
typedef short short8 __attribute__((ext_vector_type(8)));
typedef float floatx4 __attribute__((ext_vector_type(4)));

__device__ __forceinline__ float bfu2f(unsigned short u) {
    return __builtin_bit_cast(float, ((unsigned int)u) << 16);
}
__device__ __forceinline__ unsigned short f2bfu(float f) {
    unsigned int x = __builtin_bit_cast(unsigned int, f);
    unsigned int lsb = (x >> 16) & 1u;
    x += 0x7fffu + lsb;                 // round-to-nearest-even
    return (unsigned short)(x >> 16);
}
__device__ __forceinline__ unsigned int pack2(float a, float b) {
    return (unsigned int)f2bfu(a) | ((unsigned int)f2bfu(b) << 16);
}
__device__ __forceinline__ float unpk_lo(unsigned int u) {
    return __builtin_bit_cast(float, u << 16);
}
__device__ __forceinline__ float unpk_hi(unsigned int u) {
    return __builtin_bit_cast(float, u & 0xffff0000u);
}

// ===========================================================================
// FAST PATH — 2 dispatches total
// ===========================================================================

// K1: projections with self-staged weights (no separate transpose kernel).
// grid (128, 4):
//   y=0: EQ (fp32)   = entity@Wq + bq
//   y=1: EKV K-half  = entity@Wk          (bias folded into RK)
//   y=2: EKV V-half  = entity@Wv + bv
//   y=3: RKb (bf16)  = rel_table@Wk + bk  (237 rows; x>=2 exits via rbase guard)
__global__ __launch_bounds__(256) void proj_mfma(
    const float* __restrict__ entity, const float* __restrict__ rel_table,
    const float* __restrict__ Wq, const float* __restrict__ bq,
    const float* __restrict__ Wk, const float* __restrict__ bk,
    const float* __restrict__ Wv, const float* __restrict__ bv,
    float* __restrict__ EQ, unsigned short* __restrict__ EKV,
    unsigned short* __restrict__ RKb) {
    __shared__ __align__(16) unsigned short lw[128 * 136];   // [col][k] bf16

    int y = blockIdx.y;
    const float* A; const float* Wf; const float* bias; int arows;
    unsigned short* outb; int ostride, ooff, f32out;
    if (y == 0)      { A = entity;    Wf = Wq; bias = bq;      arows = M_NODES; outb = nullptr; ostride = 128; ooff = 0;   f32out = 1; }
    else if (y == 1) { A = entity;    Wf = Wk; bias = nullptr; arows = M_NODES; outb = EKV;     ostride = 256; ooff = 0;   f32out = 0; }
    else if (y == 2) { A = entity;    Wf = Wv; bias = bv;      arows = M_NODES; outb = EKV;     ostride = 256; ooff = 128; f32out = 0; }
    else             { A = rel_table; Wf = Wk; bias = bk;      arows = RREL;    outb = RKb;     ostride = 128; ooff = 0;   f32out = 0; }

    int rbase = blockIdx.x * 128;
    if (rbase >= arows) return;
    int t = threadIdx.x;

    // self-stage: Wf fp32 [k][c] -> lw bf16 [c][k], stride 136
    #pragma unroll
    for (int i = 0; i < 16; ++i) {
        int s = t + i * 256;             // 4096 float4 slots
        int k = s >> 5, c4 = s & 31;
        float4v w = *(const float4v*)&Wf[k * 128 + c4 * 4];
        #pragma unroll
        for (int jj = 0; jj < 4; ++jj)
            lw[(c4 * 4 + jj) * 136 + k] = f2bfu(w[jj]);
    }
    __syncthreads();

    int wave = t >> 6, lane = t & 63;
    int lm = lane & 15, quad = lane >> 4;
    int m0 = rbase + wave * 32;

    floatx4 acc[2][8];
    #pragma unroll
    for (int i = 0; i < 2; ++i)
        #pragma unroll
        for (int c = 0; c < 8; ++c) acc[i][c] = (floatx4){0.f, 0.f, 0.f, 0.f};

    int r0 = m0 + lm;      if (r0 >= arows) r0 = arows - 1;
    int r1 = m0 + 16 + lm; if (r1 >= arows) r1 = arows - 1;

    #pragma unroll
    for (int ks = 0; ks < 4; ++ks) {
        int koff = ks * 32 + quad * 8;
        float4v f00 = *(const float4v*)&A[r0 * 128 + koff];
        float4v f01 = *(const float4v*)&A[r0 * 128 + koff + 4];
        float4v f10 = *(const float4v*)&A[r1 * 128 + koff];
        float4v f11 = *(const float4v*)&A[r1 * 128 + koff + 4];
        short8 a0, a1;
        #pragma unroll
        for (int j = 0; j < 4; ++j) {
            a0[j]     = (short)f2bfu(f00[j]);
            a0[4 + j] = (short)f2bfu(f01[j]);
            a1[j]     = (short)f2bfu(f10[j]);
            a1[4 + j] = (short)f2bfu(f11[j]);
        }
        #pragma unroll
        for (int c = 0; c < 8; ++c) {
            short8 b = *(const short8*)&lw[(c * 16 + lm) * 136 + koff];
            acc[0][c] = __builtin_amdgcn_mfma_f32_16x16x32_bf16(a0, b, acc[0][c], 0, 0, 0);
            acc[1][c] = __builtin_amdgcn_mfma_f32_16x16x32_bf16(a1, b, acc[1][c], 0, 0, 0);
        }
    }

    #pragma unroll
    for (int c = 0; c < 8; ++c) {
        int col = c * 16 + lm;
        float bb = bias ? bias[col] : 0.0f;
        #pragma unroll
        for (int i = 0; i < 2; ++i) {
            int rb = m0 + i * 16 + quad * 4;
            #pragma unroll
            for (int j = 0; j < 4; ++j) {
                int r = rb + j;
                if (r < arows) {
                    float v = acc[i][c][j] + bb;
                    if (f32out) EQ[r * 128 + col] = v;
                    else        outb[r * ostride + ooff + col] = f2bfu(v);
                }
            }
        }
    }
}

// K2: attention gather + softmax + PV + Wo projection (replicated-row MFMA)
// + residual + LayerNorm. 8 nodes/block (512 thr, 8 waves), grid 2048.
__global__ __launch_bounds__(512, 6) void attn_wo_ln(
    const int* __restrict__ nidx, const int* __restrict__ nrel,
    const int* __restrict__ nmask,
    const float* __restrict__ EQ, const unsigned short* __restrict__ EKV,
    const unsigned short* __restrict__ RKb,
    const float* __restrict__ Wo, const float* __restrict__ bo,
    const float* __restrict__ entity,
    const float* __restrict__ gamma_, const float* __restrict__ beta_,
    float* __restrict__ OUT) {
    __shared__ __align__(16) unsigned short lwWo[128 * 136];   // Wo^T bf16 [col][k]
    __shared__ __align__(16) float oatw[8][132];               // per-wave oat row
    __shared__ float Pl[8][8][32];
    __shared__ int mix[8][32];

    int t = threadIdx.x;

    // stage Wo fp32 [k][c] -> lwWo bf16 [c][k]
    #pragma unroll
    for (int i = 0; i < 8; ++i) {
        int s = t + i * 512;             // 4096 float4 slots
        int k = s >> 5, c4 = s & 31;
        float4v w = *(const float4v*)&Wo[k * 128 + c4 * 4];
        #pragma unroll
        for (int jj = 0; jj < 4; ++jj)
            lwWo[(c4 * 4 + jj) * 136 + k] = f2bfu(w[jj]);
    }
    __syncthreads();

    int w = t >> 6, l = t & 63;
    int m = blockIdx.x * 8 + w;
    int half = l >> 5, n = l & 31;

    int mk = nmask[m * NNBR + n];
    int ix = nidx[m * NNBR + n];
    int ir = nrel[m * NNBR + n];
    if (!mk) { ix = 0; ir = 0; }
    ix = ix < 0 ? 0 : (ix > M_NODES - 1 ? M_NODES - 1 : ix);
    ir = ir < 0 ? 0 : (ir > RREL - 1 ? RREL - 1 : ir);
    if (l < 32) mix[w][l] = ix;          // wave-private, no barrier needed

    // logits for heads half*4..+3 (dims half*64..+63)
    const float4v* eq4 = (const float4v*)&EQ[m * 128 + half * 64];
    const unsigned short* kp = &EKV[ix * 256 + half * 64];
    const unsigned short* rp = &RKb[ir * 128 + half * 64];
    float acl[4] = {0.f, 0.f, 0.f, 0.f};
    #pragma unroll
    for (int c2 = 0; c2 < 8; ++c2) {
        float4v q0 = eq4[2 * c2], q1 = eq4[2 * c2 + 1];
        short8 k8 = *(const short8*)&kp[c2 * 8];
        short8 r8 = *(const short8*)&rp[c2 * 8];
        int hh = c2 >> 1;
        #pragma unroll
        for (int j = 0; j < 4; ++j) {
            acl[hh] += q0[j] * (bfu2f((unsigned short)k8[j]) + bfu2f((unsigned short)r8[j]));
            acl[hh] += q1[j] * (bfu2f((unsigned short)k8[4 + j]) + bfu2f((unsigned short)r8[4 + j]));
        }
    }
    #pragma unroll
    for (int hh = 0; hh < 4; ++hh) {
        float lf = acl[hh] * ATTN_SCALE;
        if (!mk) lf = -1e30f;
        float mx = lf;
        #pragma unroll
        for (int off = 16; off >= 1; off >>= 1) mx = fmaxf(mx, __shfl_xor(mx, off, 32));
        float p = __expf(lf - mx);
        float s = p;
        #pragma unroll
        for (int off = 16; off >= 1; off >>= 1) s += __shfl_xor(s, off, 32);
        Pl[w][half * 4 + hh][n] = p / s;
    }

    // PV: lane -> dims 2l, 2l+1 (head l>>3)
    int h0 = l >> 3;
    float o0 = 0.f, o1 = 0.f;
    #pragma unroll 8
    for (int n2 = 0; n2 < 32; ++n2) {
        float pp = Pl[w][h0][n2];
        int ixx = mix[w][n2];
        unsigned int u = *(const unsigned int*)&EKV[ixx * 256 + 128 + 2 * l];
        o0 += pp * unpk_lo(u);
        o1 += pp * unpk_hi(u);
    }
    oatw[w][2 * l]     = o0;
    oatw[w][2 * l + 1] = o1;             // same-wave produce/consume

    // Wo phase: y = oat @ Wo via replicated-row MFMA (A rows identical)
    int lm = l & 15, quad = l >> 4;
    floatx4 acc[8];
    #pragma unroll
    for (int c = 0; c < 8; ++c) acc[c] = (floatx4){0.f, 0.f, 0.f, 0.f};
    #pragma unroll
    for (int ks = 0; ks < 4; ++ks) {
        int koff = ks * 32 + quad * 8;
        float4v f0 = *(const float4v*)&oatw[w][koff];      // broadcast reads
        float4v f1 = *(const float4v*)&oatw[w][koff + 4];
        short8 a;
        #pragma unroll
        for (int j = 0; j < 4; ++j) {
            a[j]     = (short)f2bfu(f0[j]);
            a[4 + j] = (short)f2bfu(f1[j]);
        }
        #pragma unroll
        for (int c = 0; c < 8; ++c) {
            short8 b = *(const short8*)&lwWo[(c * 16 + lm) * 136 + koff];
            acc[c] = __builtin_amdgcn_mfma_f32_16x16x32_bf16(a, b, acc[c], 0, 0, 0);
        }
    }

    // epilogue: all C rows identical -> acc[c][0]. Residual + LN via width-16 shfl.
    float yv[8];
    float s1 = 0.f, s2 = 0.f;
    #pragma unroll
    for (int c = 0; c < 8; ++c) {
        int col = c * 16 + lm;
        float v = acc[c][0] + bo[col] + entity[m * 128 + col];
        yv[c] = v; s1 += v; s2 += v * v;
    }
    #pragma unroll
    for (int off = 8; off >= 1; off >>= 1) {
        s1 += __shfl_xor(s1, off, 16);
        s2 += __shfl_xor(s2, off, 16);
    }
    float mu  = s1 * (1.0f / 128.0f);
    float var = fmaxf(s2 * (1.0f / 128.0f) - mu * mu, 0.0f);
    float rs  = rsqrtf(var + LN_EPS);
    if (quad == 0) {
        #pragma unroll
        for (int c = 0; c < 8; ++c) {
            int col = c * 16 + lm;
            OUT[m * 128 + col] = (yv[c] - mu) * rs * gamma_[col] + beta_[col];
        }
    }
}

// ===========================================================================
// FALLBACK (round-5 fused kernel, ~314 µs) — used if ws too small
// ===========================================================================
__global__ __launch_bounds__(256, 6) void rga_fused(
    const float* __restrict__ entity,
    const int* __restrict__ nidx,
    const int* __restrict__ nrel,
    const int* __restrict__ nmask,
    const float* __restrict__ Wq, const float* __restrict__ bq,
    const float* __restrict__ Wk, const float* __restrict__ bk,
    const float* __restrict__ Wv, const float* __restrict__ bv,
    const float* __restrict__ Wo, const float* __restrict__ bo,
    const float* __restrict__ rel_table,
    const float* __restrict__ gamma_, const float* __restrict__ beta_,
    float* __restrict__ outp) {
    __shared__ __align__(16) float er[128];
    __shared__ __align__(16) float qv[128];
    __shared__ float qb[8];
    __shared__ __align__(16) float qk[8 * 132];
    __shared__ __align__(16) unsigned int nbvp[32 * 68];
    __shared__ float Lg[8][33];
    __shared__ __align__(16) float pv[8 * 132];
    __shared__ __align__(16) float oat[128];
    __shared__ float ypart[2][128];
    __shared__ float red[4];
    __shared__ int midx[32], mrel[32], mmask[32];

    int m = blockIdx.x;
    int t = threadIdx.x;

    if (t < 32) {
        int mk = nmask[m * NNBR + t];
        int ix = nidx[m * NNBR + t];
        int ir = nrel[m * NNBR + t];
        if (!mk) { ix = 0; ir = 0; }
        ix = ix < 0 ? 0 : (ix > M_NODES - 1 ? M_NODES - 1 : ix);
        ir = ir < 0 ? 0 : (ir > RREL - 1 ? RREL - 1 : ir);
        mmask[t] = mk; midx[t] = ix; mrel[t] = ir;
    }
    if (t >= 128) er[t - 128] = entity[m * 128 + (t - 128)];
    __syncthreads();

    {
        int half = t >> 7, d = t & 127, j0 = half * 64;
        const float4v* e4 = (const float4v*)&er[j0];
        float acc = 0.f;
        #pragma unroll 4
        for (int c = 0; c < 16; ++c) {
            float4v ev = e4[c];
            #pragma unroll
            for (int k = 0; k < 4; ++k)
                acc += ev[k] * Wq[(j0 + c * 4 + k) * 128 + d];
        }
        ypart[half][d] = acc;
    }
    __syncthreads();
    if (t < 128) qv[t] = ypart[0][t] + ypart[1][t] + bq[t];
    __syncthreads();

    #pragma unroll
    for (int rep = 0; rep < 4; ++rep) {
        int o = rep * 256 + t;
        int h = o >> 7, j = o & 127;
        const float4v* wr = (const float4v*)&Wk[j * 128 + h * 16];
        const float4v* q4 = (const float4v*)&qv[h * 16];
        float s = 0.f;
        #pragma unroll
        for (int c = 0; c < 4; ++c) {
            float4v ww = wr[c], q = q4[c];
            #pragma unroll
            for (int k = 0; k < 4; ++k) s += ww[k] * q[k];
        }
        qk[h * 132 + j] = s;
    }
    if (t < 8) {
        float s = 0.f;
        #pragma unroll
        for (int dh = 0; dh < 16; ++dh) s += qv[t * 16 + dh] * bk[t * 16 + dh];
        qb[t] = s;
    }
    __syncthreads();

    {
        int n = t >> 3, c16 = t & 7, j0 = c16 * 16;
        int ix = midx[n], ir = mrel[n];
        const float4v* ep = (const float4v*)&entity[ix * 128 + j0];
        const float4v* rp = (const float4v*)&rel_table[ir * 128 + j0];
        float ev[16], kv[16];
        #pragma unroll
        for (int c = 0; c < 4; ++c) {
            float4v e4 = ep[c], r4 = rp[c];
            #pragma unroll
            for (int k = 0; k < 4; ++k) {
                ev[c * 4 + k] = e4[k];
                kv[c * 4 + k] = e4[k] + r4[k];
            }
        }
        uint4v u0, u1;
        #pragma unroll
        for (int k = 0; k < 4; ++k) u0[k] = pack2(ev[2 * k], ev[2 * k + 1]);
        #pragma unroll
        for (int k = 0; k < 4; ++k) u1[k] = pack2(ev[8 + 2 * k], ev[9 + 2 * k]);
        *(uint4v*)&nbvp[n * 68 + c16 * 8]     = u0;
        *(uint4v*)&nbvp[n * 68 + c16 * 8 + 4] = u1;
        float acc[8];
        #pragma unroll
        for (int h = 0; h < 8; ++h) {
            const float4v* qrow = (const float4v*)&qk[h * 132 + j0];
            float s = 0.f;
            #pragma unroll
            for (int c = 0; c < 4; ++c) {
                float4v q = qrow[c];
                #pragma unroll
                for (int k = 0; k < 4; ++k) s += q[k] * kv[c * 4 + k];
            }
            acc[h] = s;
        }
        #pragma unroll
        for (int off = 1; off < 8; off <<= 1) {
            #pragma unroll
            for (int h = 0; h < 8; ++h) acc[h] += __shfl_xor(acc[h], off, 8);
        }
        if (c16 == 0) {
            #pragma unroll
            for (int h = 0; h < 8; ++h) {
                float lf = (acc[h] + qb[h]) * ATTN_SCALE;
                if (!mmask[n]) lf = -1e30f;
                Lg[h][n] = lf;
            }
        }
    }
    __syncthreads();

    {
        int h = t >> 5, n = t & 31;
        float lf = Lg[h][n];
        float mx = lf;
        #pragma unroll
        for (int off = 16; off >= 1; off >>= 1) mx = fmaxf(mx, __shfl_xor(mx, off, 32));
        float p = __expf(lf - mx);
        float s = p;
        #pragma unroll
        for (int off = 16; off >= 1; off >>= 1) s += __shfl_xor(s, off, 32);
        Lg[h][n] = p / s;
    }
    __syncthreads();

    {
        int h = t >> 5, c4 = t & 31;
        float4v a = (float4v){0.f, 0.f, 0.f, 0.f};
        #pragma unroll 8
        for (int n = 0; n < 32; ++n) {
            float p = Lg[h][n];
            unsigned int w0 = nbvp[n * 68 + c4 * 2];
            unsigned int w1 = nbvp[n * 68 + c4 * 2 + 1];
            a[0] += p * unpk_lo(w0);
            a[1] += p * unpk_hi(w0);
            a[2] += p * unpk_lo(w1);
            a[3] += p * unpk_hi(w1);
        }
        *(float4v*)&pv[h * 132 + c4 * 4] = a;
    }
    __syncthreads();

    {
        int half = t >> 7, d = t & 127, j0 = half * 64;
        int h = d >> 4;
        const float4v* p4 = (const float4v*)&pv[h * 132 + j0];
        float acc = 0.f;
        #pragma unroll 4
        for (int c = 0; c < 16; ++c) {
            float4v p = p4[c];
            #pragma unroll
            for (int k = 0; k < 4; ++k)
                acc += p[k] * Wv[(j0 + c * 4 + k) * 128 + d];
        }
        ypart[half][d] = acc;
    }
    __syncthreads();
    if (t < 128) oat[t] = ypart[0][t] + ypart[1][t] + bv[t];
    __syncthreads();

    {
        int half = t >> 7, d = t & 127, j0 = half * 64;
        const float4v* o4 = (const float4v*)&oat[j0];
        float acc = 0.f;
        #pragma unroll 4
        for (int c = 0; c < 16; ++c) {
            float4v o = o4[c];
            #pragma unroll
            for (int k = 0; k < 4; ++k)
                acc += o[k] * Wo[(j0 + c * 4 + k) * 128 + d];
        }
        ypart[half][d] = acc;
    }
    __syncthreads();

    float x = 0.f;
    if (t < 128) {
        x = er[t] + ypart[0][t] + ypart[1][t] + bo[t];
        float s1 = x, s2 = x * x;
        #pragma unroll
        for (int off = 32; off >= 1; off >>= 1) {
            s1 += __shfl_xor(s1, off, 64);
            s2 += __shfl_xor(s2, off, 64);
        }
        if ((t & 63) == 0) { red[(t >> 6) * 2] = s1; red[(t >> 6) * 2 + 1] = s2; }
    }
    __syncthreads();
    if (t < 128) {
        float mu  = (red[0] + red[2]) * (1.0f / 128.0f);
        float ms  = (red[1] + red[3]) * (1.0f / 128.0f);
        float var = fmaxf(ms - mu * mu, 0.0f);
        float rs  = rsqrtf(var + LN_EPS);
        outp[m * 128 + t] = (x - mu) * rs * gamma_[t] + beta_[t];
    }
}

// ---------------------------------------------------------------------------
extern "C" void kernel_launch(void* const* d_in, const int* in_sizes, int n_in,
                              void* d_out, int out_size, void* d_ws, size_t ws_size,
                              hipStream_t stream) {
    const float* entity    = (const float*)d_in[0];
    const int*   nidx      = (const int*)d_in[1];
    const int*   nrel      = (const int*)d_in[2];
    const int*   nmask     = (const int*)d_in[3];
    const float* Wq        = (const float*)d_in[4];
    const float* bq        = (const float*)d_in[5];
    const float* Wk        = (const float*)d_in[6];
    const float* bk        = (const float*)d_in[7];
    const float* Wv        = (const float*)d_in[8];
    const float* bv        = (const float*)d_in[9];
    const float* Wo        = (const float*)d_in[10];
    const float* bo        = (const float*)d_in[11];
    const float* rel_table = (const float*)d_in[12];
    const float* gamma_    = (const float*)d_in[13];
    const float* beta_     = (const float*)d_in[14];

    // ws layout: EKV(bf16) 8M @0 | EQ(f32) 8M @8M | RKb(bf16) 60672 @16M
    char* ws = (char*)d_ws;
    unsigned short* EKV = (unsigned short*)(ws + 0);
    float*          EQ  = (float*)(ws + 8388608);
    unsigned short* RKb = (unsigned short*)(ws + 16777216);
    const size_t NEED = 16777216 + 60672;

    if (ws_size >= NEED) {
        proj_mfma<<<dim3(128, 4), 256, 0, stream>>>(
            entity, rel_table, Wq, bq, Wk, bk, Wv, bv, EQ, EKV, RKb);
        attn_wo_ln<<<dim3(M_NODES / 8), 512, 0, stream>>>(
            nidx, nrel, nmask, EQ, EKV, RKb, Wo, bo, entity, gamma_, beta_,
            (float*)d_out);
    } else {
        rga_fused<<<dim3(M_NODES), 256, 0, stream>>>(
            entity, nidx, nrel, nmask, Wq, bq, Wk, bk, Wv, bv, Wo, bo,
            rel_table, gamma_, beta_, (float*)d_out);
    }
}

// Round 9
// 159.209 us; speedup vs baseline: 1.1273x; 1.1273x over previous
//
#include <hip/hip_runtime.h>

#define M_NODES 16384
#define NNBR 32
#define RREL 237
#define ATTN_SCALE 0.25f   // (128/8)^-0.5
#define LN_EPS 1e-5f

typedef float float4v __attribute__((ext_vector_type(4)));
typedef float float2v __attribute__((ext_vector_type(2)));
typedef unsigned int uint2v __attribute__((ext_vector_type(2)));
typedef unsigned int uint4v __attribute__((ext_vector_type(4)));
typedef short short8 __attribute__((ext_vector_type(8)));
typedef float floatx4 __attribute__((ext_vector_type(4)));

__device__ __forceinline__ float bfu2f(unsigned short u) {
    return __builtin_bit_cast(float, ((unsigned int)u) << 16);
}
__device__ __forceinline__ unsigned short f2bfu(float f) {
    unsigned int x = __builtin_bit_cast(unsigned int, f);
    unsigned int lsb = (x >> 16) & 1u;
    x += 0x7fffu + lsb;                 // round-to-nearest-even
    return (unsigned short)(x >> 16);
}
__device__ __forceinline__ unsigned int pack2(float a, float b) {
    return (unsigned int)f2bfu(a) | ((unsigned int)f2bfu(b) << 16);
}
__device__ __forceinline__ float unpk_lo(unsigned int u) {
    return __builtin_bit_cast(float, u << 16);
}
__device__ __forceinline__ float unpk_hi(unsigned int u) {
    return __builtin_bit_cast(float, u & 0xffff0000u);
}

// ===========================================================================
// FAST PATH — 4 dispatches (K0 prep, K1 proj, K2 attn, K3 wo+ln)
// ===========================================================================

// K0: prep. grid 162 x 256:
//   bx<32   : weight transpose+convert  (mat=bx>>3, slab=bx&7)
//   bx=32,33: rel_table fp32 -> RBb bf16
//   bx>=34  : entity fp32 -> EB bf16 (128 blocks)
__global__ __launch_bounds__(256) void prep(
    const float* __restrict__ Wq, const float* __restrict__ Wk,
    const float* __restrict__ Wv, const float* __restrict__ Wo,
    const float* __restrict__ entity, const float* __restrict__ rel_table,
    unsigned short* __restrict__ WqT, unsigned short* __restrict__ WkT,
    unsigned short* __restrict__ WvT, unsigned short* __restrict__ WoT,
    unsigned short* __restrict__ EB, unsigned short* __restrict__ RBb) {
    int bx = blockIdx.x;
    int t = threadIdx.x;
    if (bx < 32) {
        int mat  = bx >> 3;
        int slab = bx & 7;
        const float* W = (mat == 0) ? Wq : (mat == 1) ? Wk : (mat == 2) ? Wv : Wo;
        unsigned short* WT = (mat == 0) ? WqT : (mat == 1) ? WkT : (mat == 2) ? WvT : WoT;
        #pragma unroll
        for (int i = 0; i < 8; ++i) {
            int idx = t + 256 * i;            // 0..2047 within slab
            int r = slab * 16 + (idx >> 7);
            int c = idx & 127;
            WT[c * 128 + r] = f2bfu(W[r * 128 + c]);
        }
    } else if (bx < 34) {
        int base = (bx - 32) * 4096;          // float4 index
        const int nf4 = (RREL * 128) / 4;     // 7584
        #pragma unroll
        for (int i = 0; i < 16; ++i) {
            int s = base + t + i * 256;
            if (s < nf4) {
                float4v v = *(const float4v*)&rel_table[s * 4];
                uint2v u; u[0] = pack2(v[0], v[1]); u[1] = pack2(v[2], v[3]);
                *(uint2v*)&RBb[s * 4] = u;
            }
        }
    } else {
        int base = (bx - 34) * 4096;          // float4 index
        #pragma unroll
        for (int i = 0; i < 16; ++i) {
            int s = base + t + i * 256;
            float4v v = *(const float4v*)&entity[s * 4];
            uint2v u; u[0] = pack2(v[0], v[1]); u[1] = pack2(v[2], v[3]);
            *(uint2v*)&EB[s * 4] = u;
        }
    }
}

// K1: four projections, bf16 A (EB/RBb), pre-transposed bf16 weights. grid (128,4):
//   y=0: EQ (fp32) = entity@Wq + bq
//   y=1: EKV K-half = entity@Wk           (bias folded into RK)
//   y=2: EKV V-half = entity@Wv + bv
//   y=3: RKb = rel@Wk + bk (237 rows; x>=2 exit)
__global__ __launch_bounds__(256) void gemm4_mfma(
    const unsigned short* __restrict__ EB, const unsigned short* __restrict__ RBb,
    const unsigned short* __restrict__ WqT, const unsigned short* __restrict__ WkT,
    const unsigned short* __restrict__ WvT,
    const float* __restrict__ bq, const float* __restrict__ bk,
    const float* __restrict__ bv,
    float* __restrict__ EQ, unsigned short* __restrict__ EKV,
    unsigned short* __restrict__ RKb) {
    __shared__ __align__(16) unsigned short lw[128 * 136];

    int y = blockIdx.y;
    const unsigned short* A; const unsigned short* WT; const float* bias; int arows;
    unsigned short* outb; int ostride, ooff, f32out;
    if (y == 0)      { A = EB;  WT = WqT; bias = bq;      arows = M_NODES; outb = nullptr; ostride = 128; ooff = 0;   f32out = 1; }
    else if (y == 1) { A = EB;  WT = WkT; bias = nullptr; arows = M_NODES; outb = EKV;     ostride = 256; ooff = 0;   f32out = 0; }
    else if (y == 2) { A = EB;  WT = WvT; bias = bv;      arows = M_NODES; outb = EKV;     ostride = 256; ooff = 128; f32out = 0; }
    else             { A = RBb; WT = WkT; bias = bk;      arows = RREL;    outb = RKb;     ostride = 128; ooff = 0;   f32out = 0; }

    int rbase = blockIdx.x * 128;
    if (rbase >= arows) return;
    int t = threadIdx.x;

    // stage WT into LDS (b128 copies), stride 136 bf16
    #pragma unroll
    for (int i = 0; i < 8; ++i) {
        int ci = t + 256 * i;          // 2048 chunks of 8 bf16
        int r  = ci >> 4;
        int c8 = ci & 15;
        *(short8*)&lw[r * 136 + c8 * 8] = *(const short8*)&WT[r * 128 + c8 * 8];
    }
    __syncthreads();

    int wave = t >> 6, lane = t & 63;
    int lm = lane & 15, quad = lane >> 4;
    int m0 = rbase + wave * 32;

    floatx4 acc[2][8];
    #pragma unroll
    for (int i = 0; i < 2; ++i)
        #pragma unroll
        for (int c = 0; c < 8; ++c) acc[i][c] = (floatx4){0.f, 0.f, 0.f, 0.f};

    int r0 = m0 + lm;      if (r0 >= arows) r0 = arows - 1;
    int r1 = m0 + 16 + lm; if (r1 >= arows) r1 = arows - 1;

    #pragma unroll
    for (int ks = 0; ks < 4; ++ks) {
        int koff = ks * 32 + quad * 8;
        short8 a0 = *(const short8*)&A[r0 * 128 + koff];   // direct bf16 A-frag
        short8 a1 = *(const short8*)&A[r1 * 128 + koff];
        #pragma unroll
        for (int c = 0; c < 8; ++c) {
            short8 b = *(const short8*)&lw[(c * 16 + lm) * 136 + koff];
            acc[0][c] = __builtin_amdgcn_mfma_f32_16x16x32_bf16(a0, b, acc[0][c], 0, 0, 0);
            acc[1][c] = __builtin_amdgcn_mfma_f32_16x16x32_bf16(a1, b, acc[1][c], 0, 0, 0);
        }
    }

    #pragma unroll
    for (int c = 0; c < 8; ++c) {
        int col = c * 16 + lm;
        float bb = bias ? bias[col] : 0.0f;
        #pragma unroll
        for (int i = 0; i < 2; ++i) {
            int rb = m0 + i * 16 + quad * 4;
            #pragma unroll
            for (int j = 0; j < 4; ++j) {
                int r = rb + j;
                if (r < arows) {
                    float v = acc[i][c][j] + bb;
                    if (f32out) EQ[r * 128 + col] = v;
                    else        outb[r * ostride + ooff + col] = f2bfu(v);
                }
            }
        }
    }
}

// K2: wave-per-node attention (r7-proven) — only change: OAT written as bf16.
// grid 4096 x 256 (4 nodes/block).
__global__ __launch_bounds__(256) void attn_gather(
    const int* __restrict__ nidx, const int* __restrict__ nrel,
    const int* __restrict__ nmask,
    const float* __restrict__ EQ, const unsigned short* __restrict__ EKV,
    const unsigned short* __restrict__ RKb,
    unsigned short* __restrict__ OATb) {
    __shared__ float Pl[4][8][32];
    __shared__ int mix[4][32];

    int w = threadIdx.x >> 6, l = threadIdx.x & 63;
    int m = blockIdx.x * 4 + w;
    int half = l >> 5, n = l & 31;

    int mk = nmask[m * NNBR + n];
    int ix = nidx[m * NNBR + n];
    int ir = nrel[m * NNBR + n];
    if (!mk) { ix = 0; ir = 0; }
    ix = ix < 0 ? 0 : (ix > M_NODES - 1 ? M_NODES - 1 : ix);
    ir = ir < 0 ? 0 : (ir > RREL - 1 ? RREL - 1 : ir);
    if (l < 32) mix[w][l] = ix;

    // logits for heads half*4..+3 (dims half*64..+63)
    const float4v* eq4 = (const float4v*)&EQ[m * 128 + half * 64];
    const unsigned short* kp = &EKV[ix * 256 + half * 64];
    const unsigned short* rp = &RKb[ir * 128 + half * 64];
    float acc[4] = {0.f, 0.f, 0.f, 0.f};
    #pragma unroll
    for (int c2 = 0; c2 < 8; ++c2) {
        float4v q0 = eq4[2 * c2], q1 = eq4[2 * c2 + 1];
        short8 k8 = *(const short8*)&kp[c2 * 8];
        short8 r8 = *(const short8*)&rp[c2 * 8];
        int hh = c2 >> 1;
        #pragma unroll
        for (int j = 0; j < 4; ++j) {
            acc[hh] += q0[j] * (bfu2f((unsigned short)k8[j]) + bfu2f((unsigned short)r8[j]));
            acc[hh] += q1[j] * (bfu2f((unsigned short)k8[4 + j]) + bfu2f((unsigned short)r8[4 + j]));
        }
    }
    #pragma unroll
    for (int hh = 0; hh < 4; ++hh) {
        float lf = acc[hh] * ATTN_SCALE;
        if (!mk) lf = -1e30f;
        float mx = lf;
        #pragma unroll
        for (int off = 16; off >= 1; off >>= 1) mx = fmaxf(mx, __shfl_xor(mx, off, 32));
        float p = __expf(lf - mx);
        float s = p;
        #pragma unroll
        for (int off = 16; off >= 1; off >>= 1) s += __shfl_xor(s, off, 32);
        Pl[w][half * 4 + hh][n] = p / s;
    }
    // PV: lane -> dims 2l, 2l+1 (head l>>3); V half of EKV row
    int h0 = l >> 3;
    float o0 = 0.f, o1 = 0.f;
    #pragma unroll 8
    for (int n2 = 0; n2 < 32; ++n2) {
        float pp = Pl[w][h0][n2];
        int ixx = mix[w][n2];
        unsigned int u = *(const unsigned int*)&EKV[ixx * 256 + 128 + 2 * l];
        o0 += pp * unpk_lo(u);
        o1 += pp * unpk_hi(u);
    }
    *(unsigned int*)&OATb[m * 128 + 2 * l] = pack2(o0, o1);
}

// K3: Y = OATb@Wo + bo + entity -> LayerNorm. grid 256, 128 thr (2 waves,
// 64 rows/block). LN row-stats via width-16 shuffles in the MFMA C layout.
__global__ __launch_bounds__(128) void gemm_wo_ln(
    const unsigned short* __restrict__ OATb, const unsigned short* __restrict__ WoT,
    const float* __restrict__ bo, const float* __restrict__ entity,
    const float* __restrict__ gamma_, const float* __restrict__ beta_,
    float* __restrict__ OUT) {
    __shared__ __align__(16) unsigned short lw[128 * 136];

    int t = threadIdx.x;
    #pragma unroll
    for (int i = 0; i < 16; ++i) {
        int ci = t + 128 * i;
        int r  = ci >> 4;
        int c8 = ci & 15;
        *(short8*)&lw[r * 136 + c8 * 8] = *(const short8*)&WoT[r * 128 + c8 * 8];
    }
    __syncthreads();

    int wave = t >> 6, lane = t & 63;
    int lm = lane & 15, quad = lane >> 4;
    int rbase = blockIdx.x * 64;
    int m0 = rbase + wave * 32;

    floatx4 acc[2][8];
    #pragma unroll
    for (int i = 0; i < 2; ++i)
        #pragma unroll
        for (int c = 0; c < 8; ++c) acc[i][c] = (floatx4){0.f, 0.f, 0.f, 0.f};

    int r0 = m0 + lm, r1 = m0 + 16 + lm;
    #pragma unroll
    for (int ks = 0; ks < 4; ++ks) {
        int koff = ks * 32 + quad * 8;
        short8 a0 = *(const short8*)&OATb[r0 * 128 + koff];
        short8 a1 = *(const short8*)&OATb[r1 * 128 + koff];
        #pragma unroll
        for (int c = 0; c < 8; ++c) {
            short8 b = *(const short8*)&lw[(c * 16 + lm) * 136 + koff];
            acc[0][c] = __builtin_amdgcn_mfma_f32_16x16x32_bf16(a0, b, acc[0][c], 0, 0, 0);
            acc[1][c] = __builtin_amdgcn_mfma_f32_16x16x32_bf16(a1, b, acc[1][c], 0, 0, 0);
        }
    }

    float bb[8], gg[8], be[8];
    #pragma unroll
    for (int c = 0; c < 8; ++c) {
        int col = c * 16 + lm;
        bb[c] = bo[col]; gg[c] = gamma_[col]; be[c] = beta_[col];
    }
    #pragma unroll
    for (int i = 0; i < 2; ++i) {
        #pragma unroll
        for (int j = 0; j < 4; ++j) {
            int r = m0 + i * 16 + quad * 4 + j;
            float y[8];
            float s1 = 0.f, s2 = 0.f;
            #pragma unroll
            for (int c = 0; c < 8; ++c) {
                float v = acc[i][c][j] + bb[c] + entity[r * 128 + c * 16 + lm];
                y[c] = v; s1 += v; s2 += v * v;
            }
            #pragma unroll
            for (int off = 8; off >= 1; off >>= 1) {
                s1 += __shfl_xor(s1, off, 16);
                s2 += __shfl_xor(s2, off, 16);
            }
            float mu  = s1 * (1.0f / 128.0f);
            float var = fmaxf(s2 * (1.0f / 128.0f) - mu * mu, 0.0f);
            float rs  = rsqrtf(var + LN_EPS);
            #pragma unroll
            for (int c = 0; c < 8; ++c)
                OUT[r * 128 + c * 16 + lm] = (y[c] - mu) * rs * gg[c] + be[c];
        }
    }
}

// ===========================================================================
// FALLBACK (round-5 fused kernel, ~314 µs) — used if ws too small
// ===========================================================================
__global__ __launch_bounds__(256, 6) void rga_fused(
    const float* __restrict__ entity,
    const int* __restrict__ nidx,
    const int* __restrict__ nrel,
    const int* __restrict__ nmask,
    const float* __restrict__ Wq, const float* __restrict__ bq,
    const float* __restrict__ Wk, const float* __restrict__ bk,
    const float* __restrict__ Wv, const float* __restrict__ bv,
    const float* __restrict__ Wo, const float* __restrict__ bo,
    const float* __restrict__ rel_table,
    const float* __restrict__ gamma_, const float* __restrict__ beta_,
    float* __restrict__ outp) {
    __shared__ __align__(16) float er[128];
    __shared__ __align__(16) float qv[128];
    __shared__ float qb[8];
    __shared__ __align__(16) float qk[8 * 132];
    __shared__ __align__(16) unsigned int nbvp[32 * 68];
    __shared__ float Lg[8][33];
    __shared__ __align__(16) float pv[8 * 132];
    __shared__ __align__(16) float oat[128];
    __shared__ float ypart[2][128];
    __shared__ float red[4];
    __shared__ int midx[32], mrel[32], mmask[32];

    int m = blockIdx.x;
    int t = threadIdx.x;

    if (t < 32) {
        int mk = nmask[m * NNBR + t];
        int ix = nidx[m * NNBR + t];
        int ir = nrel[m * NNBR + t];
        if (!mk) { ix = 0; ir = 0; }
        ix = ix < 0 ? 0 : (ix > M_NODES - 1 ? M_NODES - 1 : ix);
        ir = ir < 0 ? 0 : (ir > RREL - 1 ? RREL - 1 : ir);
        mmask[t] = mk; midx[t] = ix; mrel[t] = ir;
    }
    if (t >= 128) er[t - 128] = entity[m * 128 + (t - 128)];
    __syncthreads();

    {
        int half = t >> 7, d = t & 127, j0 = half * 64;
        const float4v* e4 = (const float4v*)&er[j0];
        float acc = 0.f;
        #pragma unroll 4
        for (int c = 0; c < 16; ++c) {
            float4v ev = e4[c];
            #pragma unroll
            for (int k = 0; k < 4; ++k)
                acc += ev[k] * Wq[(j0 + c * 4 + k) * 128 + d];
        }
        ypart[half][d] = acc;
    }
    __syncthreads();
    if (t < 128) qv[t] = ypart[0][t] + ypart[1][t] + bq[t];
    __syncthreads();

    #pragma unroll
    for (int rep = 0; rep < 4; ++rep) {
        int o = rep * 256 + t;
        int h = o >> 7, j = o & 127;
        const float4v* wr = (const float4v*)&Wk[j * 128 + h * 16];
        const float4v* q4 = (const float4v*)&qv[h * 16];
        float s = 0.f;
        #pragma unroll
        for (int c = 0; c < 4; ++c) {
            float4v ww = wr[c], q = q4[c];
            #pragma unroll
            for (int k = 0; k < 4; ++k) s += ww[k] * q[k];
        }
        qk[h * 132 + j] = s;
    }
    if (t < 8) {
        float s = 0.f;
        #pragma unroll
        for (int dh = 0; dh < 16; ++dh) s += qv[t * 16 + dh] * bk[t * 16 + dh];
        qb[t] = s;
    }
    __syncthreads();

    {
        int n = t >> 3, c16 = t & 7, j0 = c16 * 16;
        int ix = midx[n], ir = mrel[n];
        const float4v* ep = (const float4v*)&entity[ix * 128 + j0];
        const float4v* rp = (const float4v*)&rel_table[ir * 128 + j0];
        float ev[16], kv[16];
        #pragma unroll
        for (int c = 0; c < 4; ++c) {
            float4v e4 = ep[c], r4 = rp[c];
            #pragma unroll
            for (int k = 0; k < 4; ++k) {
                ev[c * 4 + k] = e4[k];
                kv[c * 4 + k] = e4[k] + r4[k];
            }
        }
        uint4v u0, u1;
        #pragma unroll
        for (int k = 0; k < 4; ++k) u0[k] = pack2(ev[2 * k], ev[2 * k + 1]);
        #pragma unroll
        for (int k = 0; k < 4; ++k) u1[k] = pack2(ev[8 + 2 * k], ev[9 + 2 * k]);
        *(uint4v*)&nbvp[n * 68 + c16 * 8]     = u0;
        *(uint4v*)&nbvp[n * 68 + c16 * 8 + 4] = u1;
        float acc[8];
        #pragma unroll
        for (int h = 0; h < 8; ++h) {
            const float4v* qrow = (const float4v*)&qk[h * 132 + j0];
            float s = 0.f;
            #pragma unroll
            for (int c = 0; c < 4; ++c) {
                float4v q = qrow[c];
                #pragma unroll
                for (int k = 0; k < 4; ++k) s += q[k] * kv[c * 4 + k];
            }
            acc[h] = s;
        }
        #pragma unroll
        for (int off = 1; off < 8; off <<= 1) {
            #pragma unroll
            for (int h = 0; h < 8; ++h) acc[h] += __shfl_xor(acc[h], off, 8);
        }
        if (c16 == 0) {
            #pragma unroll
            for (int h = 0; h < 8; ++h) {
                float lf = (acc[h] + qb[h]) * ATTN_SCALE;
                if (!mmask[n]) lf = -1e30f;
                Lg[h][n] = lf;
            }
        }
    }
    __syncthreads();

    {
        int h = t >> 5, n = t & 31;
        float lf = Lg[h][n];
        float mx = lf;
        #pragma unroll
        for (int off = 16; off >= 1; off >>= 1) mx = fmaxf(mx, __shfl_xor(mx, off, 32));
        float p = __expf(lf - mx);
        float s = p;
        #pragma unroll
        for (int off = 16; off >= 1; off >>= 1) s += __shfl_xor(s, off, 32);
        Lg[h][n] = p / s;
    }
    __syncthreads();

    {
        int h = t >> 5, c4 = t & 31;
        float4v a = (float4v){0.f, 0.f, 0.f, 0.f};
        #pragma unroll 8
        for (int n = 0; n < 32; ++n) {
            float p = Lg[h][n];
            unsigned int w0 = nbvp[n * 68 + c4 * 2];
            unsigned int w1 = nbvp[n * 68 + c4 * 2 + 1];
            a[0] += p * unpk_lo(w0);
            a[1] += p * unpk_hi(w0);
            a[2] += p * unpk_lo(w1);
            a[3] += p * unpk_hi(w1);
        }
        *(float4v*)&pv[h * 132 + c4 * 4] = a;
    }
    __syncthreads();

    {
        int half = t >> 7, d = t & 127, j0 = half * 64;
        int h = d >> 4;
        const float4v* p4 = (const float4v*)&pv[h * 132 + j0];
        float acc = 0.f;
        #pragma unroll 4
        for (int c = 0; c < 16; ++c) {
            float4v p = p4[c];
            #pragma unroll
            for (int k = 0; k < 4; ++k)
                acc += p[k] * Wv[(j0 + c * 4 + k) * 128 + d];
        }
        ypart[half][d] = acc;
    }
    __syncthreads();
    if (t < 128) oat[t] = ypart[0][t] + ypart[1][t] + bv[t];
    __syncthreads();

    {
        int half = t >> 7, d = t & 127, j0 = half * 64;
        const float4v* o4 = (const float4v*)&oat[j0];
        float acc = 0.f;
        #pragma unroll 4
        for (int c = 0; c < 16; ++c) {
            float4v o = o4[c];
            #pragma unroll
            for (int k = 0; k < 4; ++k)
                acc += o[k] * Wo[(j0 + c * 4 + k) * 128 + d];
        }
        ypart[half][d] = acc;
    }
    __syncthreads();

    float x = 0.f;
    if (t < 128) {
        x = er[t] + ypart[0][t] + ypart[1][t] + bo[t];
        float s1 = x, s2 = x * x;
        #pragma unroll
        for (int off = 32; off >= 1; off >>= 1) {
            s1 += __shfl_xor(s1, off, 64);
            s2 += __shfl_xor(s2, off, 64);
        }
        if ((t & 63) == 0) { red[(t >> 6) * 2] = s1; red[(t >> 6) * 2 + 1] = s2; }
    }
    __syncthreads();
    if (t < 128) {
        float mu  = (red[0] + red[2]) * (1.0f / 128.0f);
        float ms  = (red[1] + red[3]) * (1.0f / 128.0f);
        float var = fmaxf(ms - mu * mu, 0.0f);
        float rs  = rsqrtf(var + LN_EPS);
        outp[m * 128 + t] = (x - mu) * rs * gamma_[t] + beta_[t];
    }
}

// ---------------------------------------------------------------------------
extern "C" void kernel_launch(void* const* d_in, const int* in_sizes, int n_in,
                              void* d_out, int out_size, void* d_ws, size_t ws_size,
                              hipStream_t stream) {
    const float* entity    = (const float*)d_in[0];
    const int*   nidx      = (const int*)d_in[1];
    const int*   nrel      = (const int*)d_in[2];
    const int*   nmask     = (const int*)d_in[3];
    const float* Wq        = (const float*)d_in[4];
    const float* bq        = (const float*)d_in[5];
    const float* Wk        = (const float*)d_in[6];
    const float* bk        = (const float*)d_in[7];
    const float* Wv        = (const float*)d_in[8];
    const float* bv        = (const float*)d_in[9];
    const float* Wo        = (const float*)d_in[10];
    const float* bo        = (const float*)d_in[11];
    const float* rel_table = (const float*)d_in[12];
    const float* gamma_    = (const float*)d_in[13];
    const float* beta_     = (const float*)d_in[14];

    // ws layout:
    //   EKV(bf16)  8M   @ 0
    //   EQ (f32)   8M   @ 8388608
    //   OATb(bf16) 4M   @ 16777216
    //   EB (bf16)  4M   @ 20971520
    //   RBb(bf16)  60672 @ 25165824
    //   RKb(bf16)  60672 @ 25226496
    //   WqT/WkT/WvT/WoT 32K each @ 25287168..
    char* ws = (char*)d_ws;
    unsigned short* EKV  = (unsigned short*)(ws + 0);
    float*          EQ   = (float*)(ws + 8388608);
    unsigned short* OATb = (unsigned short*)(ws + 16777216);
    unsigned short* EB   = (unsigned short*)(ws + 20971520);
    unsigned short* RBb  = (unsigned short*)(ws + 25165824);
    unsigned short* RKb  = (unsigned short*)(ws + 25226496);
    unsigned short* WqT  = (unsigned short*)(ws + 25287168);
    unsigned short* WkT  = (unsigned short*)(ws + 25319936);
    unsigned short* WvT  = (unsigned short*)(ws + 25352704);
    unsigned short* WoT  = (unsigned short*)(ws + 25385472);
    const size_t NEED = 25418240;

    if (ws_size >= NEED) {
        prep<<<dim3(162), 256, 0, stream>>>(
            Wq, Wk, Wv, Wo, entity, rel_table, WqT, WkT, WvT, WoT, EB, RBb);
        gemm4_mfma<<<dim3(128, 4), 256, 0, stream>>>(
            EB, RBb, WqT, WkT, WvT, bq, bk, bv, EQ, EKV, RKb);
        attn_gather<<<dim3(M_NODES / 4), 256, 0, stream>>>(
            nidx, nrel, nmask, EQ, EKV, RKb, OATb);
        gemm_wo_ln<<<dim3(256), 128, 0, stream>>>(
            OATb, WoT, bo, entity, gamma_, beta_, (float*)d_out);
    } else {
        rga_fused<<<dim3(M_NODES), 256, 0, stream>>>(
            entity, nidx, nrel, nmask, Wq, bq, Wk, bk, Wv, bv, Wo, bo,
            rel_table, gamma_, beta_, (float*)d_out);
    }
}

// Round 10
// 154.091 us; speedup vs baseline: 1.1648x; 1.0332x over previous
//
#include <hip/hip_runtime.h>

#define M_NODES 16384
#define NNBR 32
#define RREL 237
#define ATTN_SCALE 0.25f   // (128/8)^-0.5
#define LN_EPS 1e-5f

typedef float float4v __attribute__((ext_vector_type(4)));
typedef unsigned int uint2v __attribute__((ext_vector_type(2)));
typedef unsigned int uint4v __attribute__((ext_vector_type(4)));
typedef short short8 __attribute__((ext_vector_type(8)));
typedef float floatx4 __attribute__((ext_vector_type(4)));

__device__ __forceinline__ float bfu2f(unsigned short u) {
    return __builtin_bit_cast(float, ((unsigned int)u) << 16);
}
__device__ __forceinline__ unsigned short f2bfu(float f) {
    unsigned int x = __builtin_bit_cast(unsigned int, f);
    unsigned int lsb = (x >> 16) & 1u;
    x += 0x7fffu + lsb;                 // round-to-nearest-even
    return (unsigned short)(x >> 16);
}
__device__ __forceinline__ unsigned int pack2(float a, float b) {
    return (unsigned int)f2bfu(a) | ((unsigned int)f2bfu(b) << 16);
}
__device__ __forceinline__ float unpk_lo(unsigned int u) {
    return __builtin_bit_cast(float, u << 16);
}
__device__ __forceinline__ float unpk_hi(unsigned int u) {
    return __builtin_bit_cast(float, u & 0xffff0000u);
}

// ===========================================================================
// FAST PATH — 4 dispatches (K0 weight-prep, K1 proj, K2 attn, K3 wo+ln)
// ===========================================================================

// K0: weight transpose+convert only. grid 32: mat = bx>>3, slab = bx&7.
__global__ __launch_bounds__(256) void prep_w(
    const float* __restrict__ Wq, const float* __restrict__ Wk,
    const float* __restrict__ Wv, const float* __restrict__ Wo,
    unsigned short* __restrict__ WqT, unsigned short* __restrict__ WkT,
    unsigned short* __restrict__ WvT, unsigned short* __restrict__ WoT) {
    int mat  = blockIdx.x >> 3;
    int slab = blockIdx.x & 7;
    const float* W = (mat == 0) ? Wq : (mat == 1) ? Wk : (mat == 2) ? Wv : Wo;
    unsigned short* WT = (mat == 0) ? WqT : (mat == 1) ? WkT : (mat == 2) ? WvT : WoT;
    int t = threadIdx.x;
    #pragma unroll
    for (int i = 0; i < 8; ++i) {
        int idx = t + 256 * i;            // 0..2047 within slab
        int r = slab * 16 + (idx >> 7);
        int c = idx & 127;
        WT[c * 128 + r] = f2bfu(W[r * 128 + c]);
    }
}

// K1: four projections, fp32 A inline-converted (r7-proven cost-neutral),
// pre-transposed bf16 weights, ALL outputs bf16. grid (128, 4):
//   y=0: EQb       = entity@Wq + bq
//   y=1: EKV K-half = entity@Wk          (bias folded into RK)
//   y=2: EKV V-half = entity@Wv + bv
//   y=3: RKb        = rel@Wk + bk (237 rows; x>=2 exit)
__global__ __launch_bounds__(256) void gemm4_mfma(
    const float* __restrict__ entity, const float* __restrict__ rel_table,
    const unsigned short* __restrict__ WqT, const unsigned short* __restrict__ WkT,
    const unsigned short* __restrict__ WvT,
    const float* __restrict__ bq, const float* __restrict__ bk,
    const float* __restrict__ bv,
    unsigned short* __restrict__ EQb, unsigned short* __restrict__ EKV,
    unsigned short* __restrict__ RKb) {
    __shared__ __align__(16) unsigned short lw[128 * 136];

    int y = blockIdx.y;
    const float* A; const unsigned short* WT; const float* bias; int arows;
    unsigned short* outb; int ostride, ooff;
    if (y == 0)      { A = entity;    WT = WqT; bias = bq;      arows = M_NODES; outb = EQb; ostride = 128; ooff = 0;   }
    else if (y == 1) { A = entity;    WT = WkT; bias = nullptr; arows = M_NODES; outb = EKV; ostride = 256; ooff = 0;   }
    else if (y == 2) { A = entity;    WT = WvT; bias = bv;      arows = M_NODES; outb = EKV; ostride = 256; ooff = 128; }
    else             { A = rel_table; WT = WkT; bias = bk;      arows = RREL;    outb = RKb; ostride = 128; ooff = 0;   }

    int rbase = blockIdx.x * 128;
    if (rbase >= arows) return;
    int t = threadIdx.x;

    // stage WT into LDS (b128 copies), stride 136 bf16
    #pragma unroll
    for (int i = 0; i < 8; ++i) {
        int ci = t + 256 * i;          // 2048 chunks of 8 bf16
        int r  = ci >> 4;
        int c8 = ci & 15;
        *(short8*)&lw[r * 136 + c8 * 8] = *(const short8*)&WT[r * 128 + c8 * 8];
    }
    __syncthreads();

    int wave = t >> 6, lane = t & 63;
    int lm = lane & 15, quad = lane >> 4;
    int m0 = rbase + wave * 32;

    floatx4 acc[2][8];
    #pragma unroll
    for (int i = 0; i < 2; ++i)
        #pragma unroll
        for (int c = 0; c < 8; ++c) acc[i][c] = (floatx4){0.f, 0.f, 0.f, 0.f};

    int r0 = m0 + lm;      if (r0 >= arows) r0 = arows - 1;
    int r1 = m0 + 16 + lm; if (r1 >= arows) r1 = arows - 1;

    #pragma unroll
    for (int ks = 0; ks < 4; ++ks) {
        int koff = ks * 32 + quad * 8;
        float4v f00 = *(const float4v*)&A[r0 * 128 + koff];
        float4v f01 = *(const float4v*)&A[r0 * 128 + koff + 4];
        float4v f10 = *(const float4v*)&A[r1 * 128 + koff];
        float4v f11 = *(const float4v*)&A[r1 * 128 + koff + 4];
        short8 a0, a1;
        #pragma unroll
        for (int j = 0; j < 4; ++j) {
            a0[j]     = (short)f2bfu(f00[j]);
            a0[4 + j] = (short)f2bfu(f01[j]);
            a1[j]     = (short)f2bfu(f10[j]);
            a1[4 + j] = (short)f2bfu(f11[j]);
        }
        #pragma unroll
        for (int c = 0; c < 8; ++c) {
            short8 b = *(const short8*)&lw[(c * 16 + lm) * 136 + koff];
            acc[0][c] = __builtin_amdgcn_mfma_f32_16x16x32_bf16(a0, b, acc[0][c], 0, 0, 0);
            acc[1][c] = __builtin_amdgcn_mfma_f32_16x16x32_bf16(a1, b, acc[1][c], 0, 0, 0);
        }
    }

    #pragma unroll
    for (int c = 0; c < 8; ++c) {
        int col = c * 16 + lm;
        float bb = bias ? bias[col] : 0.0f;
        #pragma unroll
        for (int i = 0; i < 2; ++i) {
            int rb = m0 + i * 16 + quad * 4;
            #pragma unroll
            for (int j = 0; j < 4; ++j) {
                int r = rb + j;
                if (r < arows) outb[r * ostride + ooff + col] = f2bfu(acc[i][c][j] + bb);
            }
        }
    }
}

// K2: wave-per-node attention. grid 4096 x 256 (4 nodes/block).
// K-phase: lane (half,n) computes heads half*4..+3 from bf16 q/k/r (24 b128 loads).
// PV-phase: lane (dgrp=l&15 owns 8 dims, ngrp=l>>4 owns 8 nbrs) -> 8 dwordx4
// loads + xor-16/32 shuffle reduce (replaces 32 scalar dword loads).
__global__ __launch_bounds__(256) void attn_gather(
    const int* __restrict__ nidx, const int* __restrict__ nrel,
    const int* __restrict__ nmask,
    const unsigned short* __restrict__ EQb, const unsigned short* __restrict__ EKV,
    const unsigned short* __restrict__ RKb,
    unsigned short* __restrict__ OATb) {
    __shared__ float Pl[4][8][33];    // padded: PV reads 8 h's per bank-group
    __shared__ int mix[4][32];

    int w = threadIdx.x >> 6, l = threadIdx.x & 63;
    int m = blockIdx.x * 4 + w;
    int half = l >> 5, n = l & 31;

    int mk = nmask[m * NNBR + n];
    int ix = nidx[m * NNBR + n];
    int ir = nrel[m * NNBR + n];
    if (!mk) { ix = 0; ir = 0; }
    ix = ix < 0 ? 0 : (ix > M_NODES - 1 ? M_NODES - 1 : ix);
    ir = ir < 0 ? 0 : (ir > RREL - 1 ? RREL - 1 : ir);
    if (l < 32) mix[w][l] = ix;          // wave-private, no barrier needed

    // logits for heads half*4..+3 (dims half*64..+63), all-bf16 inputs
    const unsigned short* qp = &EQb[m * 128 + half * 64];
    const unsigned short* kp = &EKV[ix * 256 + half * 64];
    const unsigned short* rp = &RKb[ir * 128 + half * 64];
    float acc[4] = {0.f, 0.f, 0.f, 0.f};
    #pragma unroll
    for (int c = 0; c < 8; ++c) {
        short8 q8 = *(const short8*)&qp[c * 8];
        short8 k8 = *(const short8*)&kp[c * 8];
        short8 r8 = *(const short8*)&rp[c * 8];
        int hh = c >> 1;
        #pragma unroll
        for (int j = 0; j < 8; ++j)
            acc[hh] += bfu2f((unsigned short)q8[j]) *
                       (bfu2f((unsigned short)k8[j]) + bfu2f((unsigned short)r8[j]));
    }
    #pragma unroll
    for (int hh = 0; hh < 4; ++hh) {
        float lf = acc[hh] * ATTN_SCALE;
        if (!mk) lf = -1e30f;
        float mx = lf;
        #pragma unroll
        for (int off = 16; off >= 1; off >>= 1) mx = fmaxf(mx, __shfl_xor(mx, off, 32));
        float p = __expf(lf - mx);
        float s = p;
        #pragma unroll
        for (int off = 16; off >= 1; off >>= 1) s += __shfl_xor(s, off, 32);
        Pl[w][half * 4 + hh][n] = p / s;
    }

    // PV: dgrp owns dims dgrp*8..+7 (head dgrp>>1); ngrp covers n = ngrp+4i
    int dgrp = l & 15, ngrp = l >> 4;
    int h = dgrp >> 1;
    float o[8] = {0.f, 0.f, 0.f, 0.f, 0.f, 0.f, 0.f, 0.f};
    #pragma unroll
    for (int i = 0; i < 8; ++i) {
        int n2 = ngrp + i * 4;
        float pp = Pl[w][h][n2];
        int ixx = mix[w][n2];
        short8 v8 = *(const short8*)&EKV[ixx * 256 + 128 + dgrp * 8];
        #pragma unroll
        for (int j = 0; j < 8; ++j) o[j] += pp * bfu2f((unsigned short)v8[j]);
    }
    #pragma unroll
    for (int j = 0; j < 8; ++j) {
        o[j] += __shfl_xor(o[j], 16, 64);
        o[j] += __shfl_xor(o[j], 32, 64);
    }
    if (ngrp == 0) {
        uint4v u;
        u[0] = pack2(o[0], o[1]); u[1] = pack2(o[2], o[3]);
        u[2] = pack2(o[4], o[5]); u[3] = pack2(o[6], o[7]);
        *(uint4v*)&OATb[m * 128 + dgrp * 8] = u;
    }
}

// K3: Y = OATb@Wo + bo + entity -> LayerNorm. grid 256, 128 thr (2 waves,
// 64 rows/block). LN row-stats via width-16 shuffles in the MFMA C layout.
__global__ __launch_bounds__(128) void gemm_wo_ln(
    const unsigned short* __restrict__ OATb, const unsigned short* __restrict__ WoT,
    const float* __restrict__ bo, const float* __restrict__ entity,
    const float* __restrict__ gamma_, const float* __restrict__ beta_,
    float* __restrict__ OUT) {
    __shared__ __align__(16) unsigned short lw[128 * 136];

    int t = threadIdx.x;
    #pragma unroll
    for (int i = 0; i < 16; ++i) {
        int ci = t + 128 * i;
        int r  = ci >> 4;
        int c8 = ci & 15;
        *(short8*)&lw[r * 136 + c8 * 8] = *(const short8*)&WoT[r * 128 + c8 * 8];
    }
    __syncthreads();

    int wave = t >> 6, lane = t & 63;
    int lm = lane & 15, quad = lane >> 4;
    int rbase = blockIdx.x * 64;
    int m0 = rbase + wave * 32;

    floatx4 acc[2][8];
    #pragma unroll
    for (int i = 0; i < 2; ++i)
        #pragma unroll
        for (int c = 0; c < 8; ++c) acc[i][c] = (floatx4){0.f, 0.f, 0.f, 0.f};

    int r0 = m0 + lm, r1 = m0 + 16 + lm;
    #pragma unroll
    for (int ks = 0; ks < 4; ++ks) {
        int koff = ks * 32 + quad * 8;
        short8 a0 = *(const short8*)&OATb[r0 * 128 + koff];
        short8 a1 = *(const short8*)&OATb[r1 * 128 + koff];
        #pragma unroll
        for (int c = 0; c < 8; ++c) {
            short8 b = *(const short8*)&lw[(c * 16 + lm) * 136 + koff];
            acc[0][c] = __builtin_amdgcn_mfma_f32_16x16x32_bf16(a0, b, acc[0][c], 0, 0, 0);
            acc[1][c] = __builtin_amdgcn_mfma_f32_16x16x32_bf16(a1, b, acc[1][c], 0, 0, 0);
        }
    }

    float bb[8], gg[8], be[8];
    #pragma unroll
    for (int c = 0; c < 8; ++c) {
        int col = c * 16 + lm;
        bb[c] = bo[col]; gg[c] = gamma_[col]; be[c] = beta_[col];
    }
    #pragma unroll
    for (int i = 0; i < 2; ++i) {
        #pragma unroll
        for (int j = 0; j < 4; ++j) {
            int r = m0 + i * 16 + quad * 4 + j;
            float y[8];
            float s1 = 0.f, s2 = 0.f;
            #pragma unroll
            for (int c = 0; c < 8; ++c) {
                float v = acc[i][c][j] + bb[c] + entity[r * 128 + c * 16 + lm];
                y[c] = v; s1 += v; s2 += v * v;
            }
            #pragma unroll
            for (int off = 8; off >= 1; off >>= 1) {
                s1 += __shfl_xor(s1, off, 16);
                s2 += __shfl_xor(s2, off, 16);
            }
            float mu  = s1 * (1.0f / 128.0f);
            float var = fmaxf(s2 * (1.0f / 128.0f) - mu * mu, 0.0f);
            float rs  = rsqrtf(var + LN_EPS);
            #pragma unroll
            for (int c = 0; c < 8; ++c)
                OUT[r * 128 + c * 16 + lm] = (y[c] - mu) * rs * gg[c] + be[c];
        }
    }
}

// ===========================================================================
// FALLBACK (round-5 fused kernel, ~314 µs) — used if ws too small
// ===========================================================================
typedef unsigned int uint4f __attribute__((ext_vector_type(4)));
__global__ __launch_bounds__(256, 6) void rga_fused(
    const float* __restrict__ entity,
    const int* __restrict__ nidx,
    const int* __restrict__ nrel,
    const int* __restrict__ nmask,
    const float* __restrict__ Wq, const float* __restrict__ bq,
    const float* __restrict__ Wk, const float* __restrict__ bk,
    const float* __restrict__ Wv, const float* __restrict__ bv,
    const float* __restrict__ Wo, const float* __restrict__ bo,
    const float* __restrict__ rel_table,
    const float* __restrict__ gamma_, const float* __restrict__ beta_,
    float* __restrict__ outp) {
    __shared__ __align__(16) float er[128];
    __shared__ __align__(16) float qv[128];
    __shared__ float qb[8];
    __shared__ __align__(16) float qk[8 * 132];
    __shared__ __align__(16) unsigned int nbvp[32 * 68];
    __shared__ float Lg[8][33];
    __shared__ __align__(16) float pv[8 * 132];
    __shared__ __align__(16) float oat[128];
    __shared__ float ypart[2][128];
    __shared__ float red[4];
    __shared__ int midx[32], mrel[32], mmask[32];

    int m = blockIdx.x;
    int t = threadIdx.x;

    if (t < 32) {
        int mk = nmask[m * NNBR + t];
        int ix = nidx[m * NNBR + t];
        int ir = nrel[m * NNBR + t];
        if (!mk) { ix = 0; ir = 0; }
        ix = ix < 0 ? 0 : (ix > M_NODES - 1 ? M_NODES - 1 : ix);
        ir = ir < 0 ? 0 : (ir > RREL - 1 ? RREL - 1 : ir);
        mmask[t] = mk; midx[t] = ix; mrel[t] = ir;
    }
    if (t >= 128) er[t - 128] = entity[m * 128 + (t - 128)];
    __syncthreads();

    {
        int half = t >> 7, d = t & 127, j0 = half * 64;
        const float4v* e4 = (const float4v*)&er[j0];
        float acc = 0.f;
        #pragma unroll 4
        for (int c = 0; c < 16; ++c) {
            float4v ev = e4[c];
            #pragma unroll
            for (int k = 0; k < 4; ++k)
                acc += ev[k] * Wq[(j0 + c * 4 + k) * 128 + d];
        }
        ypart[half][d] = acc;
    }
    __syncthreads();
    if (t < 128) qv[t] = ypart[0][t] + ypart[1][t] + bq[t];
    __syncthreads();

    #pragma unroll
    for (int rep = 0; rep < 4; ++rep) {
        int o = rep * 256 + t;
        int h = o >> 7, j = o & 127;
        const float4v* wr = (const float4v*)&Wk[j * 128 + h * 16];
        const float4v* q4 = (const float4v*)&qv[h * 16];
        float s = 0.f;
        #pragma unroll
        for (int c = 0; c < 4; ++c) {
            float4v ww = wr[c], q = q4[c];
            #pragma unroll
            for (int k = 0; k < 4; ++k) s += ww[k] * q[k];
        }
        qk[h * 132 + j] = s;
    }
    if (t < 8) {
        float s = 0.f;
        #pragma unroll
        for (int dh = 0; dh < 16; ++dh) s += qv[t * 16 + dh] * bk[t * 16 + dh];
        qb[t] = s;
    }
    __syncthreads();

    {
        int n = t >> 3, c16 = t & 7, j0 = c16 * 16;
        int ix = midx[n], ir = mrel[n];
        const float4v* ep = (const float4v*)&entity[ix * 128 + j0];
        const float4v* rp = (const float4v*)&rel_table[ir * 128 + j0];
        float ev[16], kv[16];
        #pragma unroll
        for (int c = 0; c < 4; ++c) {
            float4v e4 = ep[c], r4 = rp[c];
            #pragma unroll
            for (int k = 0; k < 4; ++k) {
                ev[c * 4 + k] = e4[k];
                kv[c * 4 + k] = e4[k] + r4[k];
            }
        }
        uint4f u0, u1;
        #pragma unroll
        for (int k = 0; k < 4; ++k) u0[k] = pack2(ev[2 * k], ev[2 * k + 1]);
        #pragma unroll
        for (int k = 0; k < 4; ++k) u1[k] = pack2(ev[8 + 2 * k], ev[9 + 2 * k]);
        *(uint4f*)&nbvp[n * 68 + c16 * 8]     = u0;
        *(uint4f*)&nbvp[n * 68 + c16 * 8 + 4] = u1;
        float acc[8];
        #pragma unroll
        for (int h = 0; h < 8; ++h) {
            const float4v* qrow = (const float4v*)&qk[h * 132 + j0];
            float s = 0.f;
            #pragma unroll
            for (int c = 0; c < 4; ++c) {
                float4v q = qrow[c];
                #pragma unroll
                for (int k = 0; k < 4; ++k) s += q[k] * kv[c * 4 + k];
            }
            acc[h] = s;
        }
        #pragma unroll
        for (int off = 1; off < 8; off <<= 1) {
            #pragma unroll
            for (int h = 0; h < 8; ++h) acc[h] += __shfl_xor(acc[h], off, 8);
        }
        if (c16 == 0) {
            #pragma unroll
            for (int h = 0; h < 8; ++h) {
                float lf = (acc[h] + qb[h]) * ATTN_SCALE;
                if (!mmask[n]) lf = -1e30f;
                Lg[h][n] = lf;
            }
        }
    }
    __syncthreads();

    {
        int h = t >> 5, n = t & 31;
        float lf = Lg[h][n];
        float mx = lf;
        #pragma unroll
        for (int off = 16; off >= 1; off >>= 1) mx = fmaxf(mx, __shfl_xor(mx, off, 32));
        float p = __expf(lf - mx);
        float s = p;
        #pragma unroll
        for (int off = 16; off >= 1; off >>= 1) s += __shfl_xor(s, off, 32);
        Lg[h][n] = p / s;
    }
    __syncthreads();

    {
        int h = t >> 5, c4 = t & 31;
        float4v a = (float4v){0.f, 0.f, 0.f, 0.f};
        #pragma unroll 8
        for (int n = 0; n < 32; ++n) {
            float p = Lg[h][n];
            unsigned int w0 = nbvp[n * 68 + c4 * 2];
            unsigned int w1 = nbvp[n * 68 + c4 * 2 + 1];
            a[0] += p * unpk_lo(w0);
            a[1] += p * unpk_hi(w0);
            a[2] += p * unpk_lo(w1);
            a[3] += p * unpk_hi(w1);
        }
        *(float4v*)&pv[h * 132 + c4 * 4] = a;
    }
    __syncthreads();

    {
        int half = t >> 7, d = t & 127, j0 = half * 64;
        int h = d >> 4;
        const float4v* p4 = (const float4v*)&pv[h * 132 + j0];
        float acc = 0.f;
        #pragma unroll 4
        for (int c = 0; c < 16; ++c) {
            float4v p = p4[c];
            #pragma unroll
            for (int k = 0; k < 4; ++k)
                acc += p[k] * Wv[(j0 + c * 4 + k) * 128 + d];
        }
        ypart[half][d] = acc;
    }
    __syncthreads();
    if (t < 128) oat[t] = ypart[0][t] + ypart[1][t] + bv[t];
    __syncthreads();

    {
        int half = t >> 7, d = t & 127, j0 = half * 64;
        const float4v* o4 = (const float4v*)&oat[j0];
        float acc = 0.f;
        #pragma unroll 4
        for (int c = 0; c < 16; ++c) {
            float4v o = o4[c];
            #pragma unroll
            for (int k = 0; k < 4; ++k)
                acc += o[k] * Wo[(j0 + c * 4 + k) * 128 + d];
        }
        ypart[half][d] = acc;
    }
    __syncthreads();

    float x = 0.f;
    if (t < 128) {
        x = er[t] + ypart[0][t] + ypart[1][t] + bo[t];
        float s1 = x, s2 = x * x;
        #pragma unroll
        for (int off = 32; off >= 1; off >>= 1) {
            s1 += __shfl_xor(s1, off, 64);
            s2 += __shfl_xor(s2, off, 64);
        }
        if ((t & 63) == 0) { red[(t >> 6) * 2] = s1; red[(t >> 6) * 2 + 1] = s2; }
    }
    __syncthreads();
    if (t < 128) {
        float mu  = (red[0] + red[2]) * (1.0f / 128.0f);
        float ms  = (red[1] + red[3]) * (1.0f / 128.0f);
        float var = fmaxf(ms - mu * mu, 0.0f);
        float rs  = rsqrtf(var + LN_EPS);
        outp[m * 128 + t] = (x - mu) * rs * gamma_[t] + beta_[t];
    }
}

// ---------------------------------------------------------------------------
extern "C" void kernel_launch(void* const* d_in, const int* in_sizes, int n_in,
                              void* d_out, int out_size, void* d_ws, size_t ws_size,
                              hipStream_t stream) {
    const float* entity    = (const float*)d_in[0];
    const int*   nidx      = (const int*)d_in[1];
    const int*   nrel      = (const int*)d_in[2];
    const int*   nmask     = (const int*)d_in[3];
    const float* Wq        = (const float*)d_in[4];
    const float* bq        = (const float*)d_in[5];
    const float* Wk        = (const float*)d_in[6];
    const float* bk        = (const float*)d_in[7];
    const float* Wv        = (const float*)d_in[8];
    const float* bv        = (const float*)d_in[9];
    const float* Wo        = (const float*)d_in[10];
    const float* bo        = (const float*)d_in[11];
    const float* rel_table = (const float*)d_in[12];
    const float* gamma_    = (const float*)d_in[13];
    const float* beta_     = (const float*)d_in[14];

    // ws layout:
    //   EKV (bf16) 8M     @ 0
    //   EQb (bf16) 4M     @ 8388608
    //   OATb(bf16) 4M     @ 12582912
    //   RKb (bf16) 60672  @ 16777216
    //   WqT/WkT/WvT/WoT 32K each @ 16837888
    char* ws = (char*)d_ws;
    unsigned short* EKV  = (unsigned short*)(ws + 0);
    unsigned short* EQb  = (unsigned short*)(ws + 8388608);
    unsigned short* OATb = (unsigned short*)(ws + 12582912);
    unsigned short* RKb  = (unsigned short*)(ws + 16777216);
    unsigned short* WqT  = (unsigned short*)(ws + 16837888);
    unsigned short* WkT  = (unsigned short*)(ws + 16870656);
    unsigned short* WvT  = (unsigned short*)(ws + 16903424);
    unsigned short* WoT  = (unsigned short*)(ws + 16936192);
    const size_t NEED = 16968960;

    if (ws_size >= NEED) {
        prep_w<<<dim3(32), 256, 0, stream>>>(Wq, Wk, Wv, Wo, WqT, WkT, WvT, WoT);
        gemm4_mfma<<<dim3(128, 4), 256, 0, stream>>>(
            entity, rel_table, WqT, WkT, WvT, bq, bk, bv, EQb, EKV, RKb);
        attn_gather<<<dim3(M_NODES / 4), 256, 0, stream>>>(
            nidx, nrel, nmask, EQb, EKV, RKb, OATb);
        gemm_wo_ln<<<dim3(256), 128, 0, stream>>>(
            OATb, WoT, bo, entity, gamma_, beta_, (float*)d_out);
    } else {
        rga_fused<<<dim3(M_NODES), 256, 0, stream>>>(
            entity, nidx, nrel, nmask, Wq, bq, Wk, bk, Wv, bv, Wo, bo,
            rel_table, gamma_, beta_, (float*)d_out);
    }
}